// Round 13
// baseline (2467.938 us; speedup 1.0000x reference)
//
#include <hip/hip_runtime.h>
#include <cstdint>
#include <cstddef>

#define ZB 512
#define ZT 256
#define ZIN 64
#define ZEH 128
#define ZH 512
#define ZG 2048
#define ZNC 8
#define NBLK 256

typedef __attribute__((ext_vector_type(8))) short s8v;
typedef __attribute__((ext_vector_type(4))) float f4v;
typedef unsigned short u16;
typedef unsigned int u32;
typedef unsigned long long u64;

__device__ __forceinline__ u16 f2bf(float f){
  u32 u = __builtin_bit_cast(u32, f);
  u += 0x7FFFu + ((u >> 16) & 1u);
  return (u16)(u >> 16);
}
__device__ __forceinline__ s8v pair2v(u64 a, u64 b){
  union { u64 q[2]; s8v v; } u; u.q[0] = a; u.q[1] = b; return u.v;
}
// h layout: [buf2][bg8][half2][hg32][32 rows][16 cols] u16; chunk = 1KB/hg
__device__ __forceinline__ size_t qoff2(int buf, int bg, int hf, int hg){
  return ((((size_t)buf * 8 + bg) * 2 + hf) * 32 + hg) * 512;   // u16 elements
}
__device__ __forceinline__ u64 aload(const u64* p){
  return __hip_atomic_load(p, __ATOMIC_RELAXED, __HIP_MEMORY_SCOPE_AGENT);
}
__device__ __forceinline__ u32 fload(const u32* p){
  return __hip_atomic_load(p, __ATOMIC_RELAXED, __HIP_MEMORY_SCOPE_AGENT);
}

// ---------------------------------------------------------------------------
// Fold: Wc[2048][128] = W_ih @ W2 (bf16), bc[2048] = W_ih@b2 + b_ih + b_hh
// ---------------------------------------------------------------------------
__global__ __launch_bounds__(128)
void k_fold(const float* __restrict__ W_ih, const float* __restrict__ W2,
            const float* __restrict__ b2, const float* __restrict__ b_ih,
            const float* __restrict__ b_hh, u16* __restrict__ Wc,
            float* __restrict__ bc)
{
  const int r = blockIdx.x, c = threadIdx.x;
  const float* wr = W_ih + (size_t)r * ZH;
  float acc = 0.f;
  for (int k = 0; k < ZH; ++k) acc += wr[k] * W2[(size_t)k * ZEH + c];
  Wc[(size_t)r * ZEH + c] = f2bf(acc);
  __shared__ float red[128];
  float p = 0.f;
  for (int k = c; k < ZH; k += 128) p += wr[k] * b2[k];
  red[c] = p; __syncthreads();
  for (int s = 64; s > 0; s >>= 1){ if (c < s) red[c] += red[c + s]; __syncthreads(); }
  if (c == 0) bc[r] = red[0] + b_ih[r] + b_hh[r];
}

__global__ __launch_bounds__(256)
void k_cvt(const float* __restrict__ src, u16* __restrict__ dst, int n)
{
  int i = blockIdx.x * 256 + threadIdx.x;
  if (i < n) dst[i] = f2bf(src[i]);
}

// ---------------------------------------------------------------------------
// Encoder layer 1: X1 (t-major: [T][B][128]) = bf16(LeakyReLU(seq@W1^T+b1))
// ---------------------------------------------------------------------------
__global__ __launch_bounds__(256)
void k_enc(const float* __restrict__ seq, const float* __restrict__ W1,
           const float* __restrict__ b1, u16* __restrict__ X1)
{
  __shared__ float w1s[ZEH * 65];
  __shared__ float sqs[64 * 65];
  const int tid = threadIdx.x;
  const size_t rb = (size_t)blockIdx.x * 64;
  for (int i = tid; i < ZEH * ZIN; i += 256){ int r = i >> 6, c = i & 63; w1s[r * 65 + c] = W1[i]; }
  for (int i = tid; i < 64 * ZIN; i += 256){ int r = i >> 6, c = i & 63; sqs[r * 65 + c] = seq[(rb + r) * ZIN + c]; }
  __syncthreads();
  const int cg = tid & 31, rg = tid >> 5;
  float acc[8][4];
  #pragma unroll
  for (int i = 0; i < 8; ++i){
    #pragma unroll
    for (int j = 0; j < 4; ++j) acc[i][j] = 0.f;
  }
  for (int k = 0; k < ZIN; ++k){
    float wv[4], sv[8];
    #pragma unroll
    for (int j = 0; j < 4; ++j) wv[j] = w1s[(cg * 4 + j) * 65 + k];
    #pragma unroll
    for (int i = 0; i < 8; ++i) sv[i] = sqs[(rg * 8 + i) * 65 + k];
    #pragma unroll
    for (int i = 0; i < 8; ++i){
      #pragma unroll
      for (int j = 0; j < 4; ++j) acc[i][j] += sv[i] * wv[j];
    }
  }
  #pragma unroll
  for (int i = 0; i < 8; ++i){
    ushort4 pk;
    float v0 = acc[i][0] + b1[cg * 4 + 0]; v0 = v0 > 0.f ? v0 : 0.01f * v0;
    float v1 = acc[i][1] + b1[cg * 4 + 1]; v1 = v1 > 0.f ? v1 : 0.01f * v1;
    float v2 = acc[i][2] + b1[cg * 4 + 2]; v2 = v2 > 0.f ? v2 : 0.01f * v2;
    float v3 = acc[i][3] + b1[cg * 4 + 3]; v3 = v3 > 0.f ? v3 : 0.01f * v3;
    pk.x = f2bf(v0); pk.y = f2bf(v1); pk.z = f2bf(v2); pk.w = f2bf(v3);
    int rf = (int)rb + rg * 8 + i;            // flat b*T + t
    int b = rf >> 8, tt = rf & 255;
    *(ushort4*)(X1 + ((size_t)tt * ZB + b) * ZEH + cg * 4) = pk;
  }
}

// ---------------------------------------------------------------------------
// half-group wait: 128 per-wave flags (hg*4+w) per (bg,hf) group; lane l
// polls flags l and l+64 (64B-padded, agent scope / MALL).
// ---------------------------------------------------------------------------
__device__ __forceinline__ void qwait2(const u32* flags, int gidx, u32 target)
{
  const int l = threadIdx.x & 63;
  const u32* f0 = flags + ((size_t)(gidx * 128 + l)) * 16;
  const u32* f1 = f0 + 64 * 16;
  long long guard = 0;
  for (;;){
    u32 a = fload(f0);
    u32 b = fload(f1);
    if ((__ballot(a >= target) & __ballot(b >= target)) == ~0ull) break;
    __builtin_amdgcn_s_sleep(1);
    if (++guard > (1LL << 20)) break;   // fail loud (wrong answer), never hang
  }
}

// ---------------------------------------------------------------------------
// Cooperative LSTM, 2-slot ring (32-row half-tiles), r12 + two changes:
//  (a) EARLY PER-WAVE PUBLISH: each compute wave drains its own h stores
//      (vmcnt(0), previously paid inside syncthreads anyway) and publishes
//      its flag BEFORE the slot barrier -> flag is MALL-visible by slot end,
//      not +0.7us into the next slot (r12's post-barrier tid0 publish made
//      every consumer poll miss ~2us).
//  (b) STAGE FLAG-PREFETCH: stage issues next slot's flag loads as its last
//      act; next slot a ballot-check skips the poll on hit (qwait2 fallback).
// 256 blocks = 8 bg x 32 hg, 512 thr = 4 compute + 4 stage waves.
// ---------------------------------------------------------------------------
__global__ __launch_bounds__(512, 1)
void k_lstm(const u16* __restrict__ X1, const u16* __restrict__ Whh,
            const u16* __restrict__ Wcf, const float* __restrict__ bc,
            const u16* __restrict__ Wfcb, const float* __restrict__ bfc,
            u16* __restrict__ hbuf, float* __restrict__ out,
            u32* __restrict__ flags)
{
  __shared__ u16 hs2[2][32 * ZH];   // 2 x 32 KiB, XOR-swizzled half tiles
  const int tid = threadIdx.x;
  const int bg = (int)blockIdx.x >> 5, hg = (int)blockIdx.x & 31;
  const bool isC = (tid < 256);
  const int w = (tid >> 6) & 3, l = tid & 63;
  const int lr = l & 15, lg = l >> 4;
  const int st = tid & 255;
  const int gt = lr >> 2;

  // ---- compute-role persistent state ----
  s8v bwh[16], bwx[4];
  f4v biasv = {0.f, 0.f, 0.f, 0.f};
  float c_reg[2][2][4];   // [hf][m][r] — unroll-static indices (rule 20)
  if (isC){
    const int grow = gt * ZH + hg * 16 + w * 4 + (lr & 3);
    const u16* p = Whh + (size_t)grow * ZH + lg * 8;
    #pragma unroll
    for (int kt = 0; kt < 16; ++kt) bwh[kt] = *(const s8v*)(p + kt * 32);
    const u16* q = Wcf + (size_t)grow * ZEH + lg * 8;
    #pragma unroll
    for (int kt = 0; kt < 4; ++kt) bwx[kt] = *(const s8v*)(q + kt * 32);
    float b = bc[grow];
    biasv[0] = b; biasv[1] = b; biasv[2] = b; biasv[3] = b;
    #pragma unroll
    for (int a = 0; a < 2; ++a){
      #pragma unroll
      for (int m = 0; m < 2; ++m){
        #pragma unroll
        for (int r = 0; r < 4; ++r) c_reg[a][m][r] = 0.f;
      }
    }
  }

  // ---- stage prologue: fetch h_0[half 0] (zeros, buf 0) -> hs2[0] ----
  u32 fp0 = 0, fp1 = 0;   // prefetched flags (stage role)
  if (!isC){
    const u64* src = (const u64*)(hbuf + qoff2(0, bg, 0, 0));
    u64 va[8], vb[8];
    #pragma unroll
    for (int i = 0; i < 8; ++i){
      int cc = st + i * 256;
      va[i] = aload(src + (size_t)cc * 2);
      vb[i] = aload(src + (size_t)cc * 2 + 1);
    }
    #pragma unroll
    for (int i = 0; i < 8; ++i){
      int byte = (st + i * 256) * 16;
      int swz = byte ^ (((byte >> 5) & 3) << 4);
      *(s8v*)((char*)hs2[0] + swz) = pair2v(va[i], vb[i]);
    }
  }
  __syncthreads();

  for (int t = 0; t < ZT; ++t){
    #pragma unroll
    for (int hf = 0; hf < 2; ++hf){
      if (isC){
        // X fragments for this slot's 2 m-tiles (t-major; hides under MFMA)
        s8v ax[2][4];
        #pragma unroll
        for (int m = 0; m < 2; ++m){
          const u16* xp = X1 + ((size_t)t * ZB + (bg * 64 + hf * 32 + m * 16 + lr)) * ZEH + lg * 8;
          #pragma unroll
          for (int kt = 0; kt < 4; ++kt) ax[m][kt] = *(const s8v*)(xp + kt * 32);
        }

        const char* hb = (const char*)hs2[hf];
        f4v accm[2];
        #pragma unroll
        for (int m = 0; m < 2; ++m){
          f4v a0 = biasv;
          f4v a1 = {0.f, 0.f, 0.f, 0.f};
          #pragma unroll
          for (int kt = 0; kt < 8; ++kt){
            int byte = (2 * kt + (lg >> 1)) * 1024 + (m * 16 + lr) * 32 + (lg & 1) * 16;
            byte ^= (((byte >> 5) & 3) << 4);
            s8v av = *(const s8v*)(hb + byte);
            a0 = __builtin_amdgcn_mfma_f32_16x16x32_bf16(av, bwh[kt], a0, 0, 0, 0);
          }
          #pragma unroll
          for (int kt = 8; kt < 16; ++kt){
            int byte = (2 * kt + (lg >> 1)) * 1024 + (m * 16 + lr) * 32 + (lg & 1) * 16;
            byte ^= (((byte >> 5) & 3) << 4);
            s8v av = *(const s8v*)(hb + byte);
            a1 = __builtin_amdgcn_mfma_f32_16x16x32_bf16(av, bwh[kt], a1, 0, 0, 0);
          }
          a0 = __builtin_amdgcn_mfma_f32_16x16x32_bf16(ax[m][0], bwx[0], a0, 0, 0, 0);
          a1 = __builtin_amdgcn_mfma_f32_16x16x32_bf16(ax[m][1], bwx[1], a1, 0, 0, 0);
          a0 = __builtin_amdgcn_mfma_f32_16x16x32_bf16(ax[m][2], bwx[2], a0, 0, 0, 0);
          a1 = __builtin_amdgcn_mfma_f32_16x16x32_bf16(ax[m][3], bwx[3], a1, 0, 0, 0);
          accm[m] = a0 + a1;
        }

        // LSTM cell for both m-tiles; h -> global (agent scope)
        u16* hdst = hbuf + qoff2((t + 1) & 1, bg, hf, hg);
        #pragma unroll
        for (int m = 0; m < 2; ++m){
          #pragma unroll
          for (int r = 0; r < 4; ++r){
            float v = accm[m][r];
            float s = (gt == 2) ? 2.f : -1.f;
            float e = __expf(v * s);
            float rc = 1.f / (1.f + e);
            float a = (gt == 2) ? (1.f - 2.f * rc) : rc;   // tanh : sigmoid
            float f_ = __shfl_xor(a, 4);
            float g_ = __shfl_xor(a, 8);
            float o_ = __shfl_xor(a, 12);
            float cv = f_ * c_reg[hf][m][r] + a * g_;
            c_reg[hf][m][r] = cv;
            float e2 = __expf(2.f * cv);
            float hv = o_ * (1.f - 2.f / (1.f + e2));
            u32 bits = f2bf(hv);
            u32 lo = bits | (((u32)__shfl_xor((int)bits, 1)) << 16);
            u32 hi = (u32)__shfl_xor((int)lo, 2);
            if (lr == 0){
              u64 pk = (u64)lo | ((u64)hi << 32);
              __hip_atomic_store((u64*)(hdst + (size_t)(m * 16 + lg * 4 + r) * 16 + w * 4), pk,
                                 __ATOMIC_RELAXED, __HIP_MEMORY_SCOPE_AGENT);
            }
          }
        }
        // EARLY PER-WAVE PUBLISH: drain own stores, publish own flag before
        // the barrier -> flag is MALL-visible by slot end.
        asm volatile("s_waitcnt vmcnt(0)" ::: "memory");
        __builtin_amdgcn_sched_barrier(0);
        if (l == 0)
          __hip_atomic_store(flags + ((size_t)((bg * 2 + hf) * 128 + hg * 4 + w)) * 16,
                             (u32)(t + 1), __ATOMIC_RELAXED, __HIP_MEMORY_SCOPE_AGENT);
      } else {
        // stage: tile used NEXT slot = h_{tf}[hfT], produced at slot-1.
        // hf==0 -> (t,1) uses h_t[1];  hf==1 -> (t+1,0) uses h_{t+1}[0]
        const int hfT = hf ^ 1;
        const int tf  = t + hf;
        if (tf < ZT || hf == 0){
          if (!(t == 0 && hf == 0)){       // h_0[1] needs no wait (zeros)
            bool hit = ((__ballot(fp0 >= (u32)tf) & __ballot(fp1 >= (u32)tf)) == ~0ull);
            if (!hit) qwait2(flags, bg * 2 + hfT, (u32)tf);
          }
          const u64* src = (const u64*)(hbuf + qoff2(tf & 1, bg, hfT, 0));
          u64 va[8], vb[8];
          #pragma unroll
          for (int i = 0; i < 8; ++i){
            int cc = st + i * 256;
            va[i] = aload(src + (size_t)cc * 2);
            vb[i] = aload(src + (size_t)cc * 2 + 1);
          }
          char* dst = (char*)hs2[hf ^ 1];
          #pragma unroll
          for (int i = 0; i < 8; ++i){
            int byte = (st + i * 256) * 16;
            int swz = byte ^ (((byte >> 5) & 3) << 4);
            *(s8v*)(dst + swz) = pair2v(va[i], vb[i]);
          }
        }
        // FLAG PREFETCH for next slot's check: group (bg,hf), target t+1,
        // issued last so it samples the flags as late as possible.
        {
          const u32* f0 = flags + ((size_t)((bg * 2 + hf) * 128 + l)) * 16;
          fp0 = fload(f0);
          fp1 = fload(f0 + 64 * 16);
        }
      }
      // slot end: full drain + barrier (publishes already issued)
      __syncthreads();
    }
  }

  // epilogue: hg==0 blocks compute out = h_T @ Wfc^T + bfc (h_T in buf 0)
  if (hg == 0){
    if (tid < 64){
      qwait2(flags, bg * 2 + 0, (u32)ZT);
      qwait2(flags, bg * 2 + 1, (u32)ZT);
    }
    __syncthreads();
    if (isC){
      float ob = (lr < ZNC) ? bfc[lr] : 0.f;
      f4v acc = {ob, ob, ob, ob};
      const u16* wp = Wfcb + (size_t)lr * ZH + lg * 8;
      const int hfE = w >> 1;
      const int ric = (w & 1) * 16 + lr;     // row in 32-row chunk
      #pragma unroll
      for (int kt = 0; kt < 16; ++kt){
        int hgp = 2 * kt + (lg >> 1);
        const u64* hp = (const u64*)(hbuf + qoff2(0, bg, hfE, hgp) + (size_t)ric * 16 + (lg & 1) * 8);
        u64 a0 = aload(hp);
        u64 a1 = aload(hp + 1);
        s8v av = pair2v(a0, a1);
        s8v bv = *(const s8v*)(wp + kt * 32);
        acc = __builtin_amdgcn_mfma_f32_16x16x32_bf16(av, bv, acc, 0, 0, 0);
      }
      if (lr < ZNC){
        #pragma unroll
        for (int r = 0; r < 4; ++r)
          out[(size_t)(bg * 64 + w * 16 + lg * 4 + r) * ZNC + lr] = acc[r];
      }
    }
  }
}

// ---------------------------------------------------------------------------
extern "C" void kernel_launch(void* const* d_in, const int* in_sizes, int n_in,
                              void* d_out, int out_size, void* d_ws, size_t ws_size,
                              hipStream_t stream)
{
  const float* seq  = (const float*)d_in[0];
  const float* W1   = (const float*)d_in[1];
  const float* b1   = (const float*)d_in[2];
  const float* W2   = (const float*)d_in[3];
  const float* b2   = (const float*)d_in[4];
  const float* W_ih = (const float*)d_in[5];
  const float* W_hh = (const float*)d_in[6];
  const float* b_ih = (const float*)d_in[7];
  const float* b_hh = (const float*)d_in[8];
  const float* Wfc  = (const float*)d_in[9];
  const float* bfc  = (const float*)d_in[10];
  float* out = (float*)d_out;

  char* ws = (char*)d_ws;
  size_t off = 0;
  auto alloc = [&](size_t bytes){ void* p = ws + off; off += (bytes + 255) & ~(size_t)255; return p; };
  u16*   Wc    = (u16*)  alloc((size_t)ZG * ZEH * 2);
  float* bc    = (float*)alloc((size_t)ZG * 4);
  u16*   Whh   = (u16*)  alloc((size_t)ZG * ZH * 2);
  u16*   Wfcb  = (u16*)  alloc((size_t)16 * ZH * 2);
  u16*   X1    = (u16*)  alloc((size_t)ZB * ZT * ZEH * 2);
  u16*   hbuf  = (u16*)  alloc((size_t)2 * ZB * ZH * 2);
  u32*   flags = (u32*)  alloc((size_t)8 * 2 * 128 * 64);   // 64B-padded per (bg,hf,hg,w)

  hipMemsetAsync(flags, 0, (size_t)8 * 2 * 128 * 64, stream);
  hipMemsetAsync(hbuf, 0, (size_t)ZB * ZH * 2, stream);      // h_0 = 0 (buffer 0)
  hipMemsetAsync(Wfcb, 0, (size_t)16 * ZH * 2, stream);      // pad rows 8..15 = 0

  hipLaunchKernelGGL(k_fold, dim3(ZG), dim3(128), 0, stream, W_ih, W2, b2, b_ih, b_hh, Wc, bc);
  hipLaunchKernelGGL(k_cvt, dim3((ZG * ZH + 255) / 256), dim3(256), 0, stream, W_hh, Whh, ZG * ZH);
  hipLaunchKernelGGL(k_cvt, dim3((ZNC * ZH + 255) / 256), dim3(256), 0, stream, Wfc, Wfcb, ZNC * ZH);
  hipLaunchKernelGGL(k_enc, dim3(ZB * ZT / 64), dim3(256), 0, stream, seq, W1, b1, X1);
  hipLaunchKernelGGL(k_lstm, dim3(NBLK), dim3(512), 0, stream,
                     X1, Whh, Wc, bc, Wfcb, bfc, hbuf, out, flags);
}